// Round 1
// baseline (17.343 us; speedup 1.0000x reference)
//
#include <hip/hip_runtime.h>

#define TT 64
#define NN 128
#define PITCH 132   // float4-aligned pad; (132 % 32)*... gives 2-way-max bank aliasing in PV reads

// Fused GAT-style attention:
//   s1[c] = sum_k A[t,k,c]*W[k];  s2[c] = sum_k A[t,k,c]*W[128+k]
//   e[i,j] = leaky_relu(s1[i]+s2[j]+b0, 0.2);  alpha = softmax_j(e)
//   out[t,i,f] = sum_j alpha[i,j] * A[t,f,j]
// grid = 64*4 (blockIdx = t*4 + i-block of 32 rows), block = 256
__global__ __launch_bounds__(256, 1) void gat_fused(
    const float* __restrict__ A, const float* __restrict__ W,
    const float* __restrict__ b, float* __restrict__ out)
{
    __shared__ float A_s[NN * PITCH];      // A_s[f*PITCH + j] = A[t,f,j]   (66 KB)
    __shared__ float alpha_s[32 * PITCH];  // 16.5 KB
    __shared__ float s1_s[NN];
    __shared__ float s2_s[NN];
    __shared__ float w_s[2 * NN];

    const int tid = threadIdx.x;
    const int t  = blockIdx.x >> 2;
    const int i0 = (blockIdx.x & 3) * 32;

    const float* At = A + (size_t)t * NN * NN;
    const float b0 = b[0];

    // ---- stage A[t] (16384 floats) and W (256 floats) into LDS ----
    {
        const float4* A4 = reinterpret_cast<const float4*>(At);
        #pragma unroll
        for (int it = 0; it < 16; ++it) {
            int e4 = it * 256 + tid;            // 0..4095 float4 index
            int f  = e4 >> 5;                   // 32 float4 per row
            int j4 = (e4 & 31) << 2;
            float4 v = A4[e4];
            *reinterpret_cast<float4*>(&A_s[f * PITCH + j4]) = v;
        }
        if (tid < 64) {
            reinterpret_cast<float4*>(w_s)[tid] = reinterpret_cast<const float4*>(W)[tid];
        }
    }
    __syncthreads();

    // ---- column reductions: s1, s2 (tid < 128 each owns one column) ----
    if (tid < NN) {
        float p1 = 0.f, p2 = 0.f;
        #pragma unroll 4
        for (int k = 0; k < NN; ++k) {
            float v = A_s[k * PITCH + tid];
            p1 += v * w_s[k];
            p2 += v * w_s[NN + k];
        }
        s1_s[tid] = p1;
        s2_s[tid] = p2;
    }
    __syncthreads();

    // ---- softmax for rows i0..i0+31 (8 lanes per row, 16 j's per lane) ----
    {
        int r  = tid >> 3;        // 0..31 local row
        int jj = tid & 7;
        float s1v = s1_s[i0 + r] + b0;
        float ev[16];
        float m = -3.4e38f;
        #pragma unroll
        for (int c = 0; c < 16; ++c) {
            float x = s1v + s2_s[jj * 16 + c];
            x = (x >= 0.f) ? x : 0.2f * x;      // leaky_relu slope 0.2
            ev[c] = x;
            m = fmaxf(m, x);
        }
        m = fmaxf(m, __shfl_xor(m, 1));
        m = fmaxf(m, __shfl_xor(m, 2));
        m = fmaxf(m, __shfl_xor(m, 4));
        float s = 0.f;
        #pragma unroll
        for (int c = 0; c < 16; ++c) {
            ev[c] = __expf(ev[c] - m);
            s += ev[c];
        }
        s += __shfl_xor(s, 1);
        s += __shfl_xor(s, 2);
        s += __shfl_xor(s, 4);
        float inv = 1.0f / s;
        #pragma unroll
        for (int c = 0; c < 16; ++c) {
            alpha_s[r * PITCH + jj * 16 + c] = ev[c] * inv;
        }
    }
    __syncthreads();

    // ---- PV: out[i,f] = sum_j alpha[i,j] * A[t,f,j]; thread tile = 2i x 8f ----
    {
        int ff = tid & 15;        // f = ff + 16*r, r=0..7 (interleaved -> 2-way-max LDS aliasing)
        int ii = tid >> 4;        // i_local = 2*ii + {0,1}
        float acc0[8] = {0,0,0,0,0,0,0,0};
        float acc1[8] = {0,0,0,0,0,0,0,0};
        for (int j4 = 0; j4 < NN; j4 += 4) {
            float4 a0 = *reinterpret_cast<const float4*>(&alpha_s[(2*ii+0) * PITCH + j4]);
            float4 a1 = *reinterpret_cast<const float4*>(&alpha_s[(2*ii+1) * PITCH + j4]);
            #pragma unroll
            for (int r = 0; r < 8; ++r) {
                float4 av = *reinterpret_cast<const float4*>(&A_s[(ff + 16*r) * PITCH + j4]);
                acc0[r] += a0.x * av.x;  acc0[r] += a0.y * av.y;
                acc0[r] += a0.z * av.z;  acc0[r] += a0.w * av.w;
                acc1[r] += a1.x * av.x;  acc1[r] += a1.y * av.y;
                acc1[r] += a1.z * av.z;  acc1[r] += a1.w * av.w;
            }
        }
        float* outt = out + (size_t)t * NN * NN;
        #pragma unroll
        for (int r = 0; r < 8; ++r) {
            outt[(i0 + 2*ii + 0) * NN + ff + 16*r] = acc0[r];
            outt[(i0 + 2*ii + 1) * NN + ff + 16*r] = acc1[r];
        }
    }
}

extern "C" void kernel_launch(void* const* d_in, const int* in_sizes, int n_in,
                              void* d_out, int out_size, void* d_ws, size_t ws_size,
                              hipStream_t stream) {
    const float* A = (const float*)d_in[0];
    const float* W = (const float*)d_in[1];
    const float* b = (const float*)d_in[2];
    float* out = (float*)d_out;
    gat_fused<<<dim3(TT * 4), dim3(256), 0, stream>>>(A, W, b, out);
}